// Round 3
// baseline (838.571 us; speedup 1.0000x reference)
//
#include <hip/hip_runtime.h>

// PartialSum: x[B=2048, P=1024 * L=64] fp32 -> out[B, P] = sum over each
// contiguous 64-element partition.  512 MiB read + 8 MiB write -> ~87 us
// roofline at 6.3 TB/s.
//
// v4 (diagnostic + candidate): v1/v2/v3 (654/696/673 us) differ wildly in
// structure but share ONE invariant: the 4-step __shfl_xor (DS-pipe) reduce.
// This version eliminates ALL cross-lane traffic: one thread per partition,
// 16 sequential float4 loads privately accumulated (4 independent chains,
// line-group order so follow-up loads to the same 64B line hit L1), fully
// coalesced 256B wave-stores of the results, nontemporal streaming hints.
// If this doesn't move dur_us, the remaining time is harness reset work and
// the kernel is at its roofline.

typedef float f4 __attribute__((ext_vector_type(4)));

__global__ __launch_bounds__(256) void PartialSum_85478439125876_kernel(
    const f4* __restrict__ x4, float* __restrict__ out, long long npart) {
    long long p = (long long)blockIdx.x * blockDim.x + threadIdx.x;
    if (p >= npart) return;

    const f4* b = x4 + (p << 4);  // 16 float4 = one 256 B partition

    // Line group 0 (bytes 0..63 of the partition)
    f4 a0 = __builtin_nontemporal_load(b + 0);
    f4 a1 = __builtin_nontemporal_load(b + 1);
    f4 a2 = __builtin_nontemporal_load(b + 2);
    f4 a3 = __builtin_nontemporal_load(b + 3);
    // Line groups 1..3: 4 independent accumulator chains, loads all
    // independent so the compiler can keep many in flight.
#pragma unroll
    for (int l = 1; l < 4; ++l) {
        a0 += __builtin_nontemporal_load(b + l * 4 + 0);
        a1 += __builtin_nontemporal_load(b + l * 4 + 1);
        a2 += __builtin_nontemporal_load(b + l * 4 + 2);
        a3 += __builtin_nontemporal_load(b + l * 4 + 3);
    }

    f4 t = (a0 + a1) + (a2 + a3);
    float s = (t.x + t.y) + (t.z + t.w);

    // Consecutive lanes own consecutive partitions -> coalesced 256 B store.
    __builtin_nontemporal_store(s, out + p);
}

extern "C" void kernel_launch(void* const* d_in, const int* in_sizes, int n_in,
                              void* d_out, int out_size, void* d_ws, size_t ws_size,
                              hipStream_t stream) {
    const float* x = (const float*)d_in[0];
    float* out = (float*)d_out;

    long long n = (long long)in_sizes[0];   // 2048 * 65536 elements
    long long npart = n / 64;               // 2,097,152 partitions

    const int BLOCK = 256;
    long long grid = (npart + BLOCK - 1) / BLOCK;  // 8192 blocks, one-shot

    PartialSum_85478439125876_kernel<<<(unsigned)grid, BLOCK, 0, stream>>>(
        (const f4*)x, out, npart);
}